// Round 1
// baseline (36.975 us; speedup 1.0000x reference)
//
#include <hip/hip_runtime.h>

// Problem: B=4, N=4096, D=64, depth=2 (all fp32).
// out = MLP_dec( (Y Y^T) Y ) with Y = rownorm(MLP_enc(x)).
// Key algebraic rewrite: (Y Y^T) Y == Y (Y^T Y), and G = Y^T Y is only 64x64
// per batch. Avoids the 4096x4096 cmp matrix entirely.

constexpr int THREADS = 512;   // 8 waves: lane r = t&63 (row), q = t>>6 (output eighth)

// ---------------- K1: enc MLP + row-normalize + Gram partials ----------------
__global__ __launch_bounds__(512) void k_enc(const float* __restrict__ x,
                                             const float* __restrict__ W,
                                             float* __restrict__ y,
                                             float* __restrict__ partG,
                                             float* __restrict__ Gat,
                                             int useAtomic) {
    __shared__ float sW[2][64][64];   // 32 KB, broadcast-read (same addr across wave)
    __shared__ float sT[64][68];      // padded row tile (17.4 KB), 16B-aligned rows (68*4=272=17*16)
    __shared__ float sSq[64][8];

    const int t = threadIdx.x, r = t & 63, q = t >> 6;
    const int blk = blockIdx.x;              // 64-row tile id; batch = blk>>6
    const long base = (long)blk * 4096;

    for (int i = t; i < 2 * 64 * 64; i += THREADS) ((float*)sW)[i] = W[i];
    for (int i = t; i < 4096; i += THREADS) sT[i >> 6][i & 63] = x[base + i];
    __syncthreads();

    // ---- layer 1: h1[o] = relu(sum_i x[i] * W0[o][i]), o in [8q, 8q+8)
    float xr[64];
#pragma unroll
    for (int i = 0; i < 64; ++i) xr[i] = sT[r][i];

    float h[8];
#pragma unroll
    for (int oo = 0; oo < 8; ++oo) {
        const float4* wrow = (const float4*)sW[0][q * 8 + oo];
        float acc = 0.f;
#pragma unroll
        for (int i4 = 0; i4 < 16; ++i4) {
            float4 w = wrow[i4];
            acc += xr[4 * i4 + 0] * w.x + xr[4 * i4 + 1] * w.y +
                   xr[4 * i4 + 2] * w.z + xr[4 * i4 + 3] * w.w;
        }
        h[oo] = fmaxf(acc, 0.f);
    }
    __syncthreads();               // all x reads done before overwriting tile
#pragma unroll
    for (int oo = 0; oo < 8; ++oo) sT[r][q * 8 + oo] = h[oo];
    __syncthreads();

    // ---- layer 2
#pragma unroll
    for (int i = 0; i < 64; ++i) xr[i] = sT[r][i];     // h1 row
#pragma unroll
    for (int oo = 0; oo < 8; ++oo) {
        const float4* wrow = (const float4*)sW[1][q * 8 + oo];
        float acc = 0.f;
#pragma unroll
        for (int i4 = 0; i4 < 16; ++i4) {
            float4 w = wrow[i4];
            acc += xr[4 * i4 + 0] * w.x + xr[4 * i4 + 1] * w.y +
                   xr[4 * i4 + 2] * w.z + xr[4 * i4 + 3] * w.w;
        }
        h[oo] = fmaxf(acc, 0.f);
    }

    // ---- row norm: scale = 1/(||h2|| + 1e-6)
    float ss = 0.f;
#pragma unroll
    for (int oo = 0; oo < 8; ++oo) ss += h[oo] * h[oo];
    sSq[r][q] = ss;
    __syncthreads();               // also guarantees all h1 reads finished
    float tot = 0.f;
#pragma unroll
    for (int j = 0; j < 8; ++j) tot += sSq[r][j];
    const float scale = 1.f / (sqrtf(tot) + 1e-6f);
#pragma unroll
    for (int oo = 0; oo < 8; ++oo) sT[r][q * 8 + oo] = h[oo] * scale;
    __syncthreads();

    // ---- write y (coalesced flat copy)
    for (int i = t; i < 4096; i += THREADS) y[base + i] = sT[i >> 6][i & 63];

    // ---- Gram partial: G[k][d] over this 64-row tile; k = r, d in [8q, 8q+8)
    float g[8];
#pragma unroll
    for (int j = 0; j < 8; ++j) g[j] = 0.f;
#pragma unroll
    for (int row = 0; row < 64; ++row) {
        const float a = sT[row][r];                          // conflict-free (pad 68)
        const float4 b0 = *(const float4*)&sT[row][q * 8];   // broadcast in wave
        const float4 b1 = *(const float4*)&sT[row][q * 8 + 4];
        g[0] += a * b0.x; g[1] += a * b0.y; g[2] += a * b0.z; g[3] += a * b0.w;
        g[4] += a * b1.x; g[5] += a * b1.y; g[6] += a * b1.z; g[7] += a * b1.w;
    }
    if (useAtomic) {
        const int bb = blk >> 6;
#pragma unroll
        for (int j = 0; j < 8; ++j)
            atomicAdd(&Gat[bb * 4096 + r * 64 + q * 8 + j], g[j]);
    } else {
        float* pg = &partG[(long)blk * 4096 + r * 64 + q * 8];
        *(float4*)pg = make_float4(g[0], g[1], g[2], g[3]);
        *(float4*)(pg + 4) = make_float4(g[4], g[5], g[6], g[7]);
    }
}

// ---------------- K_red: sum 64 tile-partials per batch -> G[4][64][64] -----
__global__ __launch_bounds__(256) void k_redG(const float* __restrict__ partG,
                                              float* __restrict__ G) {
    const int e = blockIdx.x * 256 + threadIdx.x;  // 0..16383
    const int b = e >> 12, idx = e & 4095;
    float s = 0.f;
#pragma unroll 8
    for (int j = 0; j < 64; ++j) s += partG[(long)(b * 64 + j) * 4096 + idx];
    G[b * 4096 + idx] = s;
}

// ---------------- K2: z = y*G, then dec MLP ----------------------------------
__global__ __launch_bounds__(512) void k_dec(const float* __restrict__ y,
                                             const float* __restrict__ G,
                                             const float* __restrict__ W,
                                             float* __restrict__ out) {
    __shared__ float sW[2][64][64];
    __shared__ float sG[64][64];
    __shared__ float sT[64][68];

    const int t = threadIdx.x, r = t & 63, q = t >> 6;
    const int blk = blockIdx.x, bb = blk >> 6;
    const long base = (long)blk * 4096;

    for (int i = t; i < 2 * 64 * 64; i += THREADS) ((float*)sW)[i] = W[i];
    for (int i = t; i < 4096; i += THREADS) ((float*)sG)[i] = G[bb * 4096 + i];
    for (int i = t; i < 4096; i += THREADS) sT[i >> 6][i & 63] = y[base + i];
    __syncthreads();

    // ---- z[d] = sum_k y[k] * G[k][d], d in [8q, 8q+8)
    float yr[64];
#pragma unroll
    for (int i = 0; i < 64; ++i) yr[i] = sT[r][i];
    float z[8];
#pragma unroll
    for (int j = 0; j < 8; ++j) z[j] = 0.f;
#pragma unroll
    for (int k = 0; k < 64; ++k) {
        const float a = yr[k];
        const float4 g0 = *(const float4*)&sG[k][q * 8];      // broadcast
        const float4 g1 = *(const float4*)&sG[k][q * 8 + 4];
        z[0] += a * g0.x; z[1] += a * g0.y; z[2] += a * g0.z; z[3] += a * g0.w;
        z[4] += a * g1.x; z[5] += a * g1.y; z[6] += a * g1.z; z[7] += a * g1.w;
    }
    __syncthreads();               // yr reads done
#pragma unroll
    for (int j = 0; j < 8; ++j) sT[r][q * 8 + j] = z[j];
    __syncthreads();

    // ---- dec layer 1
#pragma unroll
    for (int i = 0; i < 64; ++i) yr[i] = sT[r][i];            // z row
    float h[8];
#pragma unroll
    for (int oo = 0; oo < 8; ++oo) {
        const float4* wrow = (const float4*)sW[0][q * 8 + oo];
        float acc = 0.f;
#pragma unroll
        for (int i4 = 0; i4 < 16; ++i4) {
            float4 w = wrow[i4];
            acc += yr[4 * i4 + 0] * w.x + yr[4 * i4 + 1] * w.y +
                   yr[4 * i4 + 2] * w.z + yr[4 * i4 + 3] * w.w;
        }
        h[oo] = fmaxf(acc, 0.f);
    }
    __syncthreads();               // z reads done
#pragma unroll
    for (int oo = 0; oo < 8; ++oo) sT[r][q * 8 + oo] = h[oo];
    __syncthreads();

    // ---- dec layer 2 -> out
#pragma unroll
    for (int i = 0; i < 64; ++i) yr[i] = sT[r][i];            // h row
    float o8[8];
#pragma unroll
    for (int oo = 0; oo < 8; ++oo) {
        const float4* wrow = (const float4*)sW[1][q * 8 + oo];
        float acc = 0.f;
#pragma unroll
        for (int i4 = 0; i4 < 16; ++i4) {
            float4 w = wrow[i4];
            acc += yr[4 * i4 + 0] * w.x + yr[4 * i4 + 1] * w.y +
                   yr[4 * i4 + 2] * w.z + yr[4 * i4 + 3] * w.w;
        }
        o8[oo] = fmaxf(acc, 0.f);
    }
    float* po = &out[base + r * 64 + q * 8];
    *(float4*)po = make_float4(o8[0], o8[1], o8[2], o8[3]);
    *(float4*)(po + 4) = make_float4(o8[4], o8[5], o8[6], o8[7]);
}

extern "C" void kernel_launch(void* const* d_in, const int* in_sizes, int n_in,
                              void* d_out, int out_size, void* d_ws, size_t ws_size,
                              hipStream_t stream) {
    const float* x     = (const float*)d_in[0];   // [4,4096,64]
    const float* W_enc = (const float*)d_in[1];   // [2,64,64]
    const float* W_dec = (const float*)d_in[2];   // [2,64,64]
    float* out = (float*)d_out;                   // [4,4096,64] fp32
    float* ws  = (float*)d_ws;

    const size_t Y_ELEMS = 4ull * 4096 * 64;          // 1,048,576
    const size_t G_ELEMS = 4ull * 64 * 64;            // 16,384
    const size_t needDet = (Y_ELEMS + Y_ELEMS + G_ELEMS) * sizeof(float);  // ~8.45 MB

    float* y = ws;
    if (ws_size >= needDet) {
        // deterministic two-level Gram reduction
        float* partG = ws + Y_ELEMS;                  // [256][4096]
        float* G     = partG + Y_ELEMS;               // [4][4096]
        k_enc<<<256, THREADS, 0, stream>>>(x, W_enc, y, partG, nullptr, 0);
        k_redG<<<64, 256, 0, stream>>>(partG, G);
        k_dec<<<256, THREADS, 0, stream>>>(y, G, W_dec, out);
    } else {
        // fallback: atomic Gram accumulation (fp32 rounding jitter << threshold)
        float* G = ws + Y_ELEMS;
        hipMemsetAsync(G, 0, G_ELEMS * sizeof(float), stream);
        k_enc<<<256, THREADS, 0, stream>>>(x, W_enc, y, nullptr, G, 1);
        k_dec<<<256, THREADS, 0, stream>>>(y, G, W_dec, out);
    }
}